// Round 1
// 310.451 us; speedup vs baseline: 1.1192x; 1.1192x over previous
//
#include <hip/hip_runtime.h>
#include <hip/hip_bf16.h>
#include <math.h>

#define NB 16384
#define NF 32
#define ND 64
#define NIN 2048

typedef __attribute__((ext_vector_type(8))) short fragA;   // 8 bf16
typedef __attribute__((ext_vector_type(4))) float fragC;   // 4 fp32

#define MFMA(a, b, c) __builtin_amdgcn_mfma_f32_16x16x32_bf16((a), (b), (c), 0, 0, 0)

__device__ __forceinline__ short f2bf(float f) {
    union { float f; unsigned u; } v; v.f = f;
    return (short)((v.u + 0x7fffu + ((v.u >> 16) & 1u)) >> 16);  // RNE
}
// 8 consecutive fp32 -> bf16 fragment via packed cvt (v_cvt_pk_bf16_f32)
__device__ __forceinline__ fragA cvt8(const float* p) {
    const float4 a = *(const float4*)p;
    const float4 b = *(const float4*)(p + 4);
    union { __hip_bfloat162 h[4]; fragA f; } u;
    u.h[0] = __float22bfloat162_rn(make_float2(a.x, a.y));
    u.h[1] = __float22bfloat162_rn(make_float2(a.z, a.w));
    u.h[2] = __float22bfloat162_rn(make_float2(b.x, b.y));
    u.h[3] = __float22bfloat162_rn(make_float2(b.z, b.w));
    return u.f;
}

// fast math: native exp (v_exp_f32) and rcp (v_rcp_f32)
__device__ __forceinline__ float frcp(float x) { return __builtin_amdgcn_rcpf(x); }
__device__ __forceinline__ float felu(float v) { return v > 0.f ? v : __expf(v) - 1.f; }
__device__ __forceinline__ float fsig(float g) { return __builtin_amdgcn_rcpf(1.f + __expf(-g)); }

// ---------------------------------------------------------------------------
// Prologue: weights -> bf16 B-fragment-linear layout in d_ws. (unchanged)
// ---------------------------------------------------------------------------
__global__ __launch_bounds__(256) void prep_kernel(
    const float* __restrict__ w1, const float* __restrict__ w2,
    const float* __restrict__ gw, const float* __restrict__ lw,
    const float* __restrict__ mw1, const float* __restrict__ mlw,
    const float* __restrict__ mw2, const float* __restrict__ mgw,
    const float* __restrict__ mlw2,
    short* __restrict__ wsout)
{
    int F = blockIdx.x * 256 + threadIdx.x;
    fragA o;
    if (F < 65536) {
        int mat = F >> 14;
        int f   = (F >> 9) & 31;
        int nt  = (F >> 7) & 3;
        int s   = (F >> 6) & 1;
        int l   = F & 63;
        const float* src = (mat == 0 ? w1 : mat == 1 ? w2 : mat == 2 ? gw : lw)
                           + (size_t)f * 4096;
        int n  = nt * 16 + (l & 15);
        int k0 = s * 32 + ((l >> 4) << 3);
#pragma unroll
        for (int j = 0; j < 8; ++j) o[j] = f2bf(src[(k0 + j) * 64 + n]);
    } else if (F < 90112) {
        int G  = F - 65536;
        int f  = G / 768;
        int r  = G - f * 768;
        int nt = r >> 7;
        int s  = (r >> 6) & 1;
        int l  = r & 63;
        int n  = nt * 16 + (l & 15);
        int k0 = f * 64 + s * 32 + ((l >> 4) << 3);
        if (n < 64) {
#pragma unroll
            for (int j = 0; j < 8; ++j) o[j] = f2bf(mw1[(size_t)(k0 + j) * 64 + n]);
        } else {
#pragma unroll
            for (int j = 0; j < 8; ++j) o[j] = f2bf(mlw[(size_t)(k0 + j) * 32 + (n - 64)]);
        }
    } else {
        int G2 = F - 90112;
        if (G2 < 256) {
            int nt = G2 >> 7, s = (G2 >> 6) & 1, l = G2 & 63;
            int n = nt * 16 + (l & 15);
            int k0 = s * 32 + ((l >> 4) << 3);
#pragma unroll
            for (int j = 0; j < 8; ++j) o[j] = f2bf(mw2[(k0 + j) * 32 + n]);
        } else {
            int G3 = G2 - 256;
            const float* src = (G3 < 128) ? mgw : mlw2;
            G3 &= 127;
            int nt = G3 >> 6, l = G3 & 63;
            int n = nt * 16 + (l & 15);
            int k0 = (l >> 4) << 3;
#pragma unroll
            for (int j = 0; j < 8; ++j) o[j] = f2bf(src[(k0 + j) * 32 + n]);
        }
    }
    ((fragA*)wsout)[F] = o;
}

// ---------------------------------------------------------------------------
// Fused kernel.  16 rows/block, 4 waves splitting the f-axis (8 each).
// LDS map (floats, total 8960 = 35,840 B -> 4 blocks/CU, grid = 4/CU anyway):
//   phase 1:
//     redS  [0,6208)     4 x 16x97 per-wave mask partials (plain stores,
//                        summed in stage A; replaces the atomicAdd scheme)
//     gS    [0,640)      16x36 gate pre-acts  (stage C, aliases dead redS)
//     lS    [768,1408)   16x36 lin pre-acts
//     hS1   [6208,7296)  16x68 elu(h1)
//     resS  [7296,7872)  16x36 skip path
//     h2S   [7872,8448)  16x36 h2
//   phase 2:
//     hW    [0,4352)     4 x 16x68 per-wave h buffers
//     outS  [4352,8448)  4 x 16x64 output partials
//   maskS   [8448,8960)  persists phase 1 -> phase 2
// ---------------------------------------------------------------------------
__global__ __launch_bounds__(256, 4) void fused_kernel(
    const float* __restrict__ x,
    const short* __restrict__ wfrag, const short* __restrict__ mwfrag,
    const short* __restrict__ swfrag,
    const float* __restrict__ mb1, const float* __restrict__ mb2,
    const float* __restrict__ mlb, const float* __restrict__ mgb,
    const float* __restrict__ mlb2,
    const float* __restrict__ mgamma, const float* __restrict__ mbeta,
    const float* __restrict__ b1, const float* __restrict__ b2,
    const float* __restrict__ gb, const float* __restrict__ lb,
    const float* __restrict__ gamma, const float* __restrict__ beta,
    float* __restrict__ mask_out, float* __restrict__ out)
{
    __shared__ float smem[8960];
    float* redS  = smem;            // 4 x 1552 per-wave partials
    float* gS    = smem;            // stage C (aliases dead redS)
    float* lS    = smem + 768;
    float* hS1   = smem + 6208;
    float* resS  = smem + 7296;
    float* h2S   = smem + 7872;
    float* outS  = smem + 4352;
    float* maskS = smem + 8448;

    const int tid = threadIdx.x;
    const int w = tid >> 6, l = tid & 63;
    const int row0 = blockIdx.x * 16;
    const int m = l & 15, q = l >> 4;

    const fragA* wf  = (const fragA*)wfrag;
    const fragA* mwf = (const fragA*)mwfrag;
    const fragA* swf = (const fragA*)swfrag;

    // ------------------------- Phase 1: mask -------------------------
    fragC acc[6];
#pragma unroll
    for (int nt = 0; nt < 6; ++nt) acc[nt] = (fragC){0.f, 0.f, 0.f, 0.f};

    const float* xpm = x + (size_t)(row0 + m) * NIN + q * 8;
    for (int fi = 0; fi < 8; ++fi) {
        int f = w * 8 + fi;
        const float* xp = xpm + f * ND;
        fragA a0 = cvt8(xp), a1 = cvt8(xp + 32);
        const size_t fb = (size_t)f * 768 + l;
#pragma unroll
        for (int nt = 0; nt < 6; ++nt) {
            acc[nt] = MFMA(a0, mwf[fb + nt * 128], acc[nt]);
            acc[nt] = MFMA(a1, mwf[fb + nt * 128 + 64], acc[nt]);
        }
    }
    // per-wave partial store (plain ds_write; no atomics, no zero-init)
    {
        float* myred = redS + w * 1552;
#pragma unroll
        for (int nt = 0; nt < 6; ++nt)
#pragma unroll
            for (int rg = 0; rg < 4; ++rg)
                myred[(q * 4 + rg) * 97 + nt * 16 + m] = acc[nt][rg];
    }
    __syncthreads();

    // stage A: sum 4 wave-partials; h = elu(.+mb1) -> hS1 ; res = .+mlb -> resS
    {
        int r = tid & 15, cb = tid >> 4;
#pragma unroll
        for (int i = 0; i < 6; ++i) {
            int c = cb + i * 16;
            float s = redS[r * 97 + c]        + redS[1552 + r * 97 + c]
                    + redS[3104 + r * 97 + c] + redS[4656 + r * 97 + c];
            if (c < 64) {
                hS1[r * 68 + c] = felu(s + mb1[c]);
            } else {
                resS[r * 36 + (c - 64)] = s + mlb[c - 64];
            }
        }
    }
    __syncthreads();

    // stage B (MFMA, waves 0-1): h2 = h @ mw2 + mb2 -> h2S
    if (w < 2) {
        const float* ap = hS1 + m * 68 + q * 8;
        fragA a0 = cvt8(ap), a1 = cvt8(ap + 32);
        fragC c = {0.f, 0.f, 0.f, 0.f};
        c = MFMA(a0, swf[w * 128 + l], c);
        c = MFMA(a1, swf[w * 128 + 64 + l], c);
        float bv = mb2[w * 16 + m];
#pragma unroll
        for (int rg = 0; rg < 4; ++rg)
            h2S[(q * 4 + rg) * 36 + w * 16 + m] = c[rg] + bv;
    }
    __syncthreads();

    // stage C (MFMA, all waves): gate (waves 0-1) / lin (waves 2-3) pre-acts
    {
        int ntc = w & 1;
        int isl = w >> 1;
        fragA a = cvt8(h2S + m * 36 + q * 8);          // K=32
        fragC c = {0.f, 0.f, 0.f, 0.f};
        c = MFMA(a, swf[256 + isl * 128 + ntc * 64 + l], c);
        float* dst = isl ? lS : gS;
#pragma unroll
        for (int rg = 0; rg < 4; ++rg)
            dst[(q * 4 + rg) * 36 + ntc * 16 + m] = c[rg];
    }
    __syncthreads();

    // stage D: pre = sigmoid(g+mgb)*(l+mlb2)+res ; LN(F=32)+softmax (wave 0)
    if (w == 0) {
        int r2 = l >> 2, c0 = (l & 3) * 8;
        float pre[8];
#pragma unroll
        for (int i = 0; i < 8; ++i) {
            int c = c0 + i;
            float gg = gS[r2 * 36 + c] + mgb[c];
            float ll = lS[r2 * 36 + c] + mlb2[c];
            pre[i] = ll * fsig(gg) + resS[r2 * 36 + c];
        }
        // single-pass mean/var: s1 and s2 chains run concurrently
        float s1 = 0.f, s2 = 0.f;
#pragma unroll
        for (int i = 0; i < 8; ++i) { s1 += pre[i]; s2 += pre[i] * pre[i]; }
        s1 += __shfl_xor(s1, 1); s2 += __shfl_xor(s2, 1);
        s1 += __shfl_xor(s1, 2); s2 += __shfl_xor(s2, 2);
        float mean = s1 * (1.f / 32.f);
        float var  = s2 * (1.f / 32.f) - mean * mean;
        float inv  = rsqrtf(fmaxf(var, 0.f) + 1e-5f);
        float ln[8]; float mx = -3.4e38f;
#pragma unroll
        for (int i = 0; i < 8; ++i) {
            ln[i] = (pre[i] - mean) * inv * mgamma[c0 + i] + mbeta[c0 + i];
            mx = fmaxf(mx, ln[i]);
        }
        mx = fmaxf(mx, __shfl_xor(mx, 1));
        mx = fmaxf(mx, __shfl_xor(mx, 2));
        float ssum = 0.f;
#pragma unroll
        for (int i = 0; i < 8; ++i) { ln[i] = __expf(ln[i] - mx); ssum += ln[i]; }
        ssum += __shfl_xor(ssum, 1); ssum += __shfl_xor(ssum, 2);
        float rs = frcp(ssum);
        float* mo = mask_out + (size_t)(row0 + r2) * 32 + c0;
        *(float4*)mo       = (float4){ln[0] * rs, ln[1] * rs, ln[2] * rs, ln[3] * rs};
        *(float4*)(mo + 4) = (float4){ln[4] * rs, ln[5] * rs, ln[6] * rs, ln[7] * rs};
#pragma unroll
        for (int i = 0; i < 8; ++i) maskS[r2 * 32 + c0 + i] = ln[i] * rs;
    }
    __syncthreads();

    // ------------------------- Phase 2: GRNs -------------------------
    float* hW = smem + w * 1088;   // per-wave 16x68

    fragC oac[4];
#pragma unroll
    for (int nt = 0; nt < 4; ++nt) oac[nt] = (fragC){0.f, 0.f, 0.f, 0.f};

    for (int fi = 0; fi < 8; ++fi) {
        const int f = w * 8 + fi;
        const size_t base1 = (size_t)f * 512 + l;
        const size_t base2 = (size_t)(NF + f) * 512 + l;
        const size_t baseg = (size_t)(2 * NF + f) * 512 + l;
        const size_t basel = (size_t)(3 * NF + f) * 512 + l;

        // GEMM1: h1 = elu(x @ w1 + b1) -> hW (A direct from global)
        const float* xp = xpm + f * ND;
        fragA a0 = cvt8(xp), a1 = cvt8(xp + 32);
        fragC c1[4];
#pragma unroll
        for (int nt = 0; nt < 4; ++nt) {
            fragC c = {0.f, 0.f, 0.f, 0.f};
            c = MFMA(a0, wf[base1 + nt * 128], c);
            c = MFMA(a1, wf[base1 + nt * 128 + 64], c);
            c1[nt] = c;
        }
        // prefetch GEMM2 weight frags: L2 latency hides under epilogue+LDS RT
        fragA w2f[8];
#pragma unroll
        for (int j = 0; j < 4; ++j) {
            w2f[j]     = wf[base2 + j * 128];
            w2f[j + 4] = wf[base2 + j * 128 + 64];
        }
#pragma unroll
        for (int nt = 0; nt < 4; ++nt) {
            float bv = b1[f * 64 + nt * 16 + m];
            int col = nt * 16 + m;
#pragma unroll
            for (int rg = 0; rg < 4; ++rg)
                hW[(q * 4 + rg) * 68 + col] = felu(c1[nt][rg] + bv);
        }
        // GEMM2: h2 = h1 @ w2 + b2 -> hW
        const float* ap = hW + m * 68 + q * 8;
        fragA h0 = cvt8(ap), h1 = cvt8(ap + 32);
        fragC c2[4];
#pragma unroll
        for (int nt = 0; nt < 4; ++nt) {
            fragC c = {0.f, 0.f, 0.f, 0.f};
            c = MFMA(h0, w2f[nt], c);
            c = MFMA(h1, w2f[nt + 4], c);
            c2[nt] = c;
        }
        // issue residual + mask loads early so they're ready after GEMM3/4
        float xres[4][4];
#pragma unroll
        for (int rg = 0; rg < 4; ++rg)
#pragma unroll
            for (int nt = 0; nt < 4; ++nt)
                xres[rg][nt] = x[(size_t)(row0 + q * 4 + rg) * NIN + f * ND + nt * 16 + m];
        float mk[4];
#pragma unroll
        for (int rg = 0; rg < 4; ++rg) mk[rg] = maskS[(q * 4 + rg) * 32 + f];
#pragma unroll
        for (int nt = 0; nt < 4; ++nt) {
            float bv = b2[f * 64 + nt * 16 + m];
            int col = nt * 16 + m;
#pragma unroll
            for (int rg = 0; rg < 4; ++rg)
                hW[(q * 4 + rg) * 68 + col] = c2[nt][rg] + bv;
        }
        // GEMM3+4 + epilogue
        const float* ap2 = hW + m * 68 + q * 8;
        fragA g0 = cvt8(ap2), g1 = cvt8(ap2 + 32);
        fragC ga[4], la[4];
#pragma unroll
        for (int nt = 0; nt < 4; ++nt) {
            fragC g = {0.f, 0.f, 0.f, 0.f}, li = {0.f, 0.f, 0.f, 0.f};
            g  = MFMA(g0, wf[baseg + nt * 128], g);
            g  = MFMA(g1, wf[baseg + nt * 128 + 64], g);
            li = MFMA(g0, wf[basel + nt * 128], li);
            li = MFMA(g1, wf[basel + nt * 128 + 64], li);
            ga[nt] = g; la[nt] = li;
        }
        float gbv[4], lbv[4], gmv[4], btv[4];
#pragma unroll
        for (int nt = 0; nt < 4; ++nt) {
            int cidx = f * 64 + nt * 16 + m;
            gbv[nt] = gb[cidx]; lbv[nt] = lb[cidx];
            gmv[nt] = gamma[cidx]; btv[nt] = beta[cidx];
        }
#pragma unroll
        for (int rg = 0; rg < 4; ++rg) {
            float val[4];
#pragma unroll
            for (int nt = 0; nt < 4; ++nt) {
                float gg = ga[nt][rg] + gbv[nt];
                float ll = la[nt][rg] + lbv[nt];
                val[nt] = ll * fsig(gg) + xres[rg][nt];
            }
            // single-pass mean/var: halves the serial shuffle-chain depth
            float s1 = 0.f, s2 = 0.f;
#pragma unroll
            for (int nt = 0; nt < 4; ++nt) { s1 += val[nt]; s2 += val[nt] * val[nt]; }
            s1 += __shfl_xor(s1, 1); s2 += __shfl_xor(s2, 1);
            s1 += __shfl_xor(s1, 2); s2 += __shfl_xor(s2, 2);
            s1 += __shfl_xor(s1, 4); s2 += __shfl_xor(s2, 4);
            s1 += __shfl_xor(s1, 8); s2 += __shfl_xor(s2, 8);
            float mean = s1 * (1.f / 64.f);
            float var  = s2 * (1.f / 64.f) - mean * mean;
            float inv  = rsqrtf(fmaxf(var, 0.f) + 1e-5f);
#pragma unroll
            for (int nt = 0; nt < 4; ++nt) {
                float vec = (val[nt] - mean) * inv * gmv[nt] + btv[nt];
                oac[nt][rg] += mk[rg] * vec;
            }
        }
    }

    // cross-wave output reduction
#pragma unroll
    for (int nt = 0; nt < 4; ++nt)
#pragma unroll
        for (int rg = 0; rg < 4; ++rg)
            outS[w * 1024 + (q * 4 + rg) * 64 + nt * 16 + m] = oac[nt][rg];
    __syncthreads();
    {
        int t4 = tid * 4;
        int r = t4 >> 6, c = t4 & 63;
        float v[4];
#pragma unroll
        for (int j = 0; j < 4; ++j) {
            v[j] = outS[r * 64 + c + j] + outS[1024 + r * 64 + c + j]
                 + outS[2048 + r * 64 + c + j] + outS[3072 + r * 64 + c + j];
        }
        *(float4*)(out + (size_t)(row0 + r) * 64 + c) = (float4){v[0], v[1], v[2], v[3]};
    }
}

// ---------------------------------------------------------------------------
extern "C" void kernel_launch(void* const* d_in, const int* in_sizes, int n_in,
                              void* d_out, int out_size, void* d_ws, size_t ws_size,
                              hipStream_t stream) {
    const float* x      = (const float*)d_in[0];
    const float* mw1    = (const float*)d_in[1];
    const float* mb1    = (const float*)d_in[2];
    const float* mw2    = (const float*)d_in[3];
    const float* mb2    = (const float*)d_in[4];
    const float* mlw    = (const float*)d_in[5];
    const float* mlb    = (const float*)d_in[6];
    const float* mgw    = (const float*)d_in[7];
    const float* mgb    = (const float*)d_in[8];
    const float* mlw2   = (const float*)d_in[9];
    const float* mlb2   = (const float*)d_in[10];
    const float* mgamma = (const float*)d_in[11];
    const float* mbeta  = (const float*)d_in[12];
    const float* w1     = (const float*)d_in[13];
    const float* b1     = (const float*)d_in[14];
    const float* w2     = (const float*)d_in[15];
    const float* b2     = (const float*)d_in[16];
    const float* gw     = (const float*)d_in[17];
    const float* gb     = (const float*)d_in[18];
    const float* lw     = (const float*)d_in[19];
    const float* lb     = (const float*)d_in[20];
    const float* gamma  = (const float*)d_in[21];
    const float* beta   = (const float*)d_in[22];

    float* out  = (float*)d_out;                 // [B,64]
    float* mask = out + (size_t)NB * 64;         // [B,32]

    short* wfrag  = (short*)d_ws;                // 65536 frags (grn weights)
    short* mwfrag = wfrag + (size_t)65536 * 8;   // 24576 frags (mask big GEMM)
    short* swfrag = wfrag + (size_t)90112 * 8;   // 512 frags (mw2/mgw/mlw2)

    hipLaunchKernelGGL(prep_kernel, dim3(354), dim3(256), 0, stream,
                       w1, w2, gw, lw, mw1, mlw, mw2, mgw, mlw2, wfrag);
    hipLaunchKernelGGL(fused_kernel, dim3(NB / 16), dim3(256), 0, stream,
                       x, wfrag, mwfrag, swfrag,
                       mb1, mb2, mlb, mgb, mlb2, mgamma, mbeta,
                       b1, b2, gb, lb, gamma, beta,
                       mask, out);
}